// Round 12
// baseline (302.064 us; speedup 1.0000x reference)
//
#include <hip/hip_runtime.h>

// ============================================================================
// Fused rCM attention block: qkv-proj -> flash attention -> skip-fuse -> proj
// B=4, N=2048, C=1024, H=16, Dh=64.  All matmuls on bf16 MFMA (2% abs tol).
//
// R16: barrier-free 1-wave GEMM core (AITER-style counted vmcnt).
//  Evidence: R11/-12% (dbuf+barrier), R13/null (L2 placement), R14/-23%
//  (big tile+barrier) => the block-wide barrier's implicit vmcnt(0) drain
//  is the ceiling. 1-wave blocks need NO barrier: the wave's own counted
//  s_waitcnt vmcnt(8) orders its global_load_lds vs its ds_reads.
//  64x64 tile/wave, BK=32, dbuf, 2-deep prefetch; stage(t+2) placed AFTER
//  the MFMAs (their lgkmcnt-enforced ds_read retirement makes the buffer
//  overwrite deterministically safe). 16KB LDS -> 10 blocks/CU.
//  vmcnt ledger: prologue tiles {0,1}=16 loads; iter t: wait vmcnt(8)
//  [tile t done, t+1 in flight; t=31 -> vmcnt(0)]; compute; stage t+2 (+8).
//  attn reverted to R13 exactly (R15's setprio/bf16-epilogue: -4.8us,
//  4-wave lockstep attn is the m190 null regime for T5).
// Carried: R12 4-dispatch pipeline, attn XCD swizzle, R9 raw v_exp_f32.
// ============================================================================

typedef unsigned short ushort_t;
typedef __bf16 bf16x8 __attribute__((ext_vector_type(8)));
typedef float f32x4 __attribute__((ext_vector_type(4)));

#define GAS __attribute__((address_space(1)))
#define LAS __attribute__((address_space(3)))

static __device__ __forceinline__ ushort_t f2bf(float f) {
  union { float f; unsigned int u; } v; v.f = f;
  unsigned int r = v.u + 0x7fffu + ((v.u >> 16) & 1u);  // RNE
  return (ushort_t)(r >> 16);
}

static __device__ __forceinline__ void async16(const void* g, void* l) {
  __builtin_amdgcn_global_load_lds((const GAS unsigned int*)g,
                                   (LAS unsigned int*)l, 16, 0, 0);
}

// ----------------------------------------------------------- prep kernel ----
// blockIdx range dispatch:
//   [0, 8192)          : x fp32 -> bf16 (4 elems/thread)
//   [8192, 11264)      : Wqkv transpose+cvt (1024x3072 -> 3072x1024 bf16)
//   [11264, 12288)     : Wproj transpose+cvt (1024x1024 -> 1024x1024 bf16)
__global__ __launch_bounds__(256) void prep_kernel(
    const float* __restrict__ x, ushort_t* __restrict__ Xbf,
    const float* __restrict__ Wqkv, ushort_t* __restrict__ WqkvT,
    const float* __restrict__ Wproj, ushort_t* __restrict__ WprojT) {
  __shared__ float tile[32][33];
  const int bid = (int)blockIdx.x, tid = threadIdx.x;
  if (bid < 8192) {
    int i = (bid * 256 + tid) * 4;
    float4 v = *(const float4*)(x + i);
    ushort4 o = make_ushort4(f2bf(v.x), f2bf(v.y), f2bf(v.z), f2bf(v.w));
    *(ushort4*)(Xbf + i) = o;
    return;
  }
  const float* in;
  ushort_t* out;
  int R, C, bx, by;
  if (bid < 11264) {
    int q = bid - 8192;
    by = q / 96; bx = q - by * 96;
    in = Wqkv; out = WqkvT; R = 1024; C = 3072;
  } else {
    int p = bid - 11264;
    bx = p & 31; by = p >> 5;
    in = Wproj; out = WprojT; R = 1024; C = 1024;
  }
  int bc = bx * 32, br = by * 32;
  int tx = tid & 31, ty = tid >> 5;
#pragma unroll
  for (int i = 0; i < 32; i += 8)
    tile[ty + i][tx] = in[(size_t)(br + ty + i) * C + bc + tx];
  __syncthreads();
#pragma unroll
  for (int i = 0; i < 32; i += 8)
    out[(size_t)(bc + ty + i) * R + br + tx] = f2bf(tile[tx][ty + i]);
}

// -------------------------------------- 64x64 1-wave GEMM core, BK=32 ------
// No barriers. Double-buffered As/Bs[2][64*32]; 8 async16 per stage (4 A,
// 4 B); 2 tiles in flight. Counted vmcnt: wait vmcnt(8) = tile t landed,
// tile t+1 still flying (vmcnt(0) only on the last tile). stage(t+2)
// overwrites buf[t&1] AFTER the MFMAs consumed its ds_reads (lgkmcnt-safe).
// Chunk swizzle: row r (4x16B chunks), position p holds global chunk
// (p - r)&3; lane (lr,quad) reads position (quad+row)&3 -> global chunk
// quad; 8-lane phases hit disjoint bank pairs (2-way = free).
static __device__ __forceinline__ void gemm64_core(
    const ushort_t* __restrict__ A, const ushort_t* __restrict__ Bt, int K,
    int m0, int n0, ushort_t* As, ushort_t* Bs, f32x4 acc[4][4]) {
  const int lane = threadIdx.x & 63;
  const int lr = lane & 15, quad = lane >> 4;

  auto stage = [&](int kb, int buf) {
#pragma unroll
    for (int u = 0; u < 4; ++u) {
      int f = u * 64 + lane;
      int r = f >> 2;
      int cg = (((f & 3) - (r & 3)) & 3) * 8;   // pre-swizzled source chunk
      async16(A + (size_t)(m0 + r) * K + kb + cg, As + buf * 2048 + u * 512);
      async16(Bt + (size_t)(n0 + r) * K + kb + cg, Bs + buf * 2048 + u * 512);
    }
  };
  stage(0, 0);
  stage(32, 1);

  const int nk = K >> 5;
  for (int t = 0; t < nk; ++t) {
    if (t + 1 < nk) asm volatile("s_waitcnt vmcnt(8)" ::: "memory");
    else            asm volatile("s_waitcnt vmcnt(0)" ::: "memory");
    const ushort_t* As0 = As + (t & 1) * 2048;
    const ushort_t* Bs0 = Bs + (t & 1) * 2048;
    bf16x8 af[4], bfr[4];
#pragma unroll
    for (int i = 0; i < 4; ++i) {
      int row = i * 16 + lr;
      int ch = ((quad + row) & 3) * 8;          // swizzled read chunk
      af[i]  = *(const bf16x8*)(As0 + row * 32 + ch);
      bfr[i] = *(const bf16x8*)(Bs0 + row * 32 + ch);
    }
#pragma unroll
    for (int i = 0; i < 4; ++i)
#pragma unroll
      for (int j = 0; j < 4; ++j)
        acc[i][j] = __builtin_amdgcn_mfma_f32_16x16x32_bf16(af[i], bfr[j], acc[i][j], 0, 0, 0);
    if (t + 2 < nk) stage((t + 2) << 5, t & 1); // prefetch 2 ahead
  }
}

// ------------------------------------------------------------ QKV GEMM -----
// X[8192][1024] @ Wqkv -> Q (pre-scaled by 0.125*log2e), K bf16 [B,H,N,Dh];
// V bf16 [B,H,Dh,N'] with PV-frag key permutation. bias fused.
// Grid 6144 = 128 m-tiles x 48 n-tiles; A-panel sharers (bid stride 128)
// land on one XCD (128 % 8 == 0) -> A reuse in one L2.
__global__ __launch_bounds__(64, 4) void gemm_qkv_kernel(
    const ushort_t* __restrict__ Xbf, const ushort_t* __restrict__ Wt,
    const float* __restrict__ bqkv, ushort_t* __restrict__ Qb,
    ushort_t* __restrict__ Kb, ushort_t* __restrict__ Vb) {
  __shared__ __align__(16) ushort_t As[2 * 64 * 32];
  __shared__ __align__(16) ushort_t Bs[2 * 64 * 32];
  const int bid = (int)blockIdx.x;
  const int m0 = (bid & 127) << 6;
  const int n0 = (bid >> 7) << 6;
  f32x4 acc[4][4];
#pragma unroll
  for (int i = 0; i < 4; ++i)
#pragma unroll
    for (int j = 0; j < 4; ++j) acc[i][j] = f32x4{0.f, 0.f, 0.f, 0.f};
  gemm64_core(Xbf, Wt, 1024, m0, n0, As, Bs, acc);

  const int lane = threadIdx.x & 63;
  const int col = lane & 15, quad = lane >> 4;
  const int b = m0 >> 11;
  const float C1 = 0.18033688011112042f;  // 0.125 * log2(e)
#pragma unroll
  for (int j = 0; j < 4; ++j) {
    int jc = n0 + j * 16 + col;
    float bj = bqkv[jc];
    int which = jc >> 10, rem = jc & 1023;
    int hh = rem >> 6, d = rem & 63;
    if (which == 2) {
      size_t vb2 = ((size_t)(b * 16 + hh) * 64 + d) * 2048;
#pragma unroll
      for (int i = 0; i < 4; ++i) {
        int nbase = (m0 + i * 16 + quad * 4) & 2047;
        // PV-frag permutation: n' = p*32 + qq*8 + sh*4 + rr
        int npos = (nbase & ~31) | (((nbase >> 2) & 3) << 3) | (((nbase >> 4) & 1) << 2);
        ushort4 pk = make_ushort4(f2bf(acc[i][j][0] + bj), f2bf(acc[i][j][1] + bj),
                                  f2bf(acc[i][j][2] + bj), f2bf(acc[i][j][3] + bj));
        *(ushort4*)(Vb + vb2 + npos) = pk;
      }
    } else {
      ushort_t* dst = which == 0 ? Qb : Kb;
      float sc = which == 0 ? C1 : 1.0f;
      size_t base = ((size_t)(b * 16 + hh) * 2048) * 64 + d;
#pragma unroll
      for (int i = 0; i < 4; ++i)
#pragma unroll
        for (int r = 0; r < 4; ++r) {
          int nseq = (m0 + i * 16 + quad * 4 + r) & 2047;
          dst[base + (size_t)nseq * 64] = f2bf((acc[i][j][r] + bj) * sc);
        }
    }
  }
}

// ------------------------------------------------------------ Out GEMM -----
// Grid 2048 = 128 m-tiles x 16 n-tiles.
__global__ __launch_bounds__(64, 4) void gemm_out_kernel(
    const ushort_t* __restrict__ Hbf, const ushort_t* __restrict__ Wt,
    const float* __restrict__ bproj, float* __restrict__ out) {
  __shared__ __align__(16) ushort_t As[2 * 64 * 32];
  __shared__ __align__(16) ushort_t Bs[2 * 64 * 32];
  const int bid = (int)blockIdx.x;
  const int m0 = (bid & 127) << 6;
  const int n0 = (bid >> 7) << 6;
  f32x4 acc[4][4];
#pragma unroll
  for (int i = 0; i < 4; ++i)
#pragma unroll
    for (int j = 0; j < 4; ++j) acc[i][j] = f32x4{0.f, 0.f, 0.f, 0.f};
  gemm64_core(Hbf, Wt, 1024, m0, n0, As, Bs, acc);

  const int lane = threadIdx.x & 63;
  const int col = lane & 15, quad = lane >> 4;
#pragma unroll
  for (int j = 0; j < 4; ++j) {
    int jc = n0 + j * 16 + col;
    float bj = bproj[jc];
#pragma unroll
    for (int i = 0; i < 4; ++i)
#pragma unroll
      for (int r = 0; r < 4; ++r) {
        int m = m0 + i * 16 + quad * 4 + r;
        out[(size_t)m * 1024 + jc] = acc[i][j][r] + bj;
      }
  }
}

// ------------------------------------------------------ flash attention ----
// Block = 128 Q-rows (4 waves x 32 rows = 2 qtiles of 16); 64-key tiles,
// double-buffered, one barrier per tile. Per 32-key pair: 8 QK MFMAs (S^T),
// 32 exp + 16 perm, 8 PV + 2 l-MFMAs; V-frag = one b128 read.
// Chunked XCD swizzle: XCD x serves bh in [8x,8x+8) -> 4MB KV set per L2.
// Skip coefficients computed inline from t (coeff kernel folded in).
__global__ __launch_bounds__(256, 4) void attn_kernel(
    const ushort_t* __restrict__ Qb, const ushort_t* __restrict__ Kb,
    const ushort_t* __restrict__ Vb, const float* __restrict__ x,
    const float* __restrict__ t, ushort_t* __restrict__ Hbf) {
  // Ks[buf][key r][d]: 8-elem chunk at position p holds global chunk p^(r&7)
  // Vs[buf][d][key']: 8-key chunk at position p holds global chunk p^(d&7)
  __shared__ __align__(16) ushort_t Ks[2][64 * 64];
  __shared__ __align__(16) ushort_t Vs[2][64 * 64];

  const int tid = threadIdx.x, w = tid >> 6, lane = tid & 63;
  const int m = lane & 15, q = lane >> 4;
  // bijective chunked XCD swizzle (grid 1024 = 8 XCD x 128)
  const int bid = (int)blockIdx.x;
  const int wg = (bid & 7) * 128 + (bid >> 3);
  const int bh = wg >> 4, rowbase = ((wg & 15) << 7) + w * 32;

  const ushort_t* Qg = Qb + ((size_t)bh * 2048 + rowbase) * 64;
  const ushort_t* Kg = Kb + (size_t)bh * 2048 * 64;
  const ushort_t* Vg = Vb + (size_t)bh * 64 * 2048;  // [d][n']

  bf16x8 qf[2][2];
#pragma unroll
  for (int qt = 0; qt < 2; ++qt) {
    qf[qt][0] = *(const bf16x8*)(Qg + (qt * 16 + m) * 64 + q * 8);
    qf[qt][1] = *(const bf16x8*)(Qg + (qt * 16 + m) * 64 + 32 + q * 8);
  }

  auto stage = [&](int kt, int buf) {
#pragma unroll
    for (int i = 0; i < 2; ++i) {   // K: 64 keys x 64 d, swizzled
      int f = i * 256 + tid;
      int r = f >> 3, g = (f & 7) ^ (r & 7);
      async16(Kg + (size_t)(kt * 64 + r) * 64 + g * 8,
              Ks[buf] + (size_t)(i * 256 + w * 64) * 8);
    }
#pragma unroll
    for (int i = 0; i < 2; ++i) {   // V^T: 64 d x 64 keys, swizzled
      int f = i * 256 + tid;
      int d = f >> 3, g = (f & 7) ^ (d & 7);
      async16(Vg + (size_t)d * 2048 + kt * 64 + g * 8,
              Vs[buf] + (size_t)(i * 256 + w * 64) * 8);
    }
  };
  stage(0, 0);

  f32x4 oacc[2][4], lacc[2];
#pragma unroll
  for (int qt = 0; qt < 2; ++qt) {
    lacc[qt] = f32x4{0.f, 0.f, 0.f, 0.f};
#pragma unroll
    for (int dt = 0; dt < 4; ++dt) oacc[qt][dt] = f32x4{0.f, 0.f, 0.f, 0.f};
  }

  const float C2 = -23.083120654223414f;  // -16*log2(e)
  const f32x4 c2v = {C2, C2, C2, C2};
  const int mk = m & 7;
  union { bf16x8 v; unsigned int u[4]; } onesu;
#pragma unroll
  for (int h = 0; h < 4; ++h) onesu.u[h] = 0x3F803F80u;  // bf16 1.0 x2
  const bf16x8 ones = onesu.v;

#pragma unroll 2
  for (int kt = 0; kt < 32; ++kt) {
    const int cur = kt & 1;
    __syncthreads();                       // tile kt staged & prior reads done
    if (kt < 31) stage(kt + 1, cur ^ 1);   // prefetch in flight during compute
    const ushort_t* K0 = Ks[cur];
    const ushort_t* V0 = Vs[cur];

#pragma unroll
    for (int p = 0; p < 2; ++p) {          // 32-key pair of 16-key subtiles
      // ---- S^T: A = K-frag, B = Q-frag ----
      f32x4 st[2][2];
#pragma unroll
      for (int sh = 0; sh < 2; ++sh) {
        int s = p * 2 + sh;
        bf16x8 kf0 = *(const bf16x8*)(K0 + (s * 16 + m) * 64 + (q ^ mk) * 8);
        bf16x8 kf1 = *(const bf16x8*)(K0 + (s * 16 + m) * 64 + ((q + 4) ^ mk) * 8);
#pragma unroll
        for (int qt = 0; qt < 2; ++qt) {
          f32x4 a = __builtin_amdgcn_mfma_f32_16x16x32_bf16(kf0, qf[qt][0], c2v, 0, 0, 0);
          st[sh][qt] = __builtin_amdgcn_mfma_f32_16x16x32_bf16(kf1, qf[qt][1], a, 0, 0, 0);
        }
      }
      // ---- exp + truncating pack into PV B-frags (k = q*8 + sh*4 + rr) ----
      bf16x8 pf[2];
#pragma unroll
      for (int qt = 0; qt < 2; ++qt) {
        float pv[8];
#pragma unroll
        for (int sh = 0; sh < 2; ++sh)
#pragma unroll
          for (int rr = 0; rr < 4; ++rr)
            pv[sh * 4 + rr] = __builtin_amdgcn_exp2f(st[sh][qt][rr]);  // raw v_exp_f32
        union { bf16x8 v; unsigned int u[4]; } pk;
#pragma unroll
        for (int h = 0; h < 4; ++h)
          pk.u[h] = __builtin_amdgcn_perm(__float_as_uint(pv[2 * h + 1]),
                                          __float_as_uint(pv[2 * h]), 0x07060302);
        pf[qt] = pk.v;
      }
      // ---- O^T += V'-frag @ P^T; l += ones @ P^T (all on MFMA pipe) ----
#pragma unroll
      for (int dt = 0; dt < 4; ++dt) {
        bf16x8 vf = *(const bf16x8*)(V0 + (dt * 16 + m) * 64 + ((p * 4 + q) ^ mk) * 8);
#pragma unroll
        for (int qt = 0; qt < 2; ++qt)
          oacc[qt][dt] = __builtin_amdgcn_mfma_f32_16x16x32_bf16(vf, pf[qt], oacc[qt][dt], 0, 0, 0);
      }
#pragma unroll
      for (int qt = 0; qt < 2; ++qt)
        lacc[qt] = __builtin_amdgcn_mfma_f32_16x16x32_bf16(ones, pf[qt], lacc[qt], 0, 0, 0);
    }
  }

  // ---- epilogue: h = c_skip*x + c_out*(o/l); l = lacc[qt][0] (col = m) ----
  // skip coefficients inline (was coeff_kernel): mean over the 4 batch t's
  float cs = 0.f, co = 0.f;
#pragma unroll
  for (int i = 0; i < 4; ++i) {
    float ti = t[i];
    float d = 1.f + ti * ti;        // sigma_data = 1
    cs += 1.f / d;
    co += ti / sqrtf(d);
  }
  cs *= 0.25f; co *= 0.25f;

  const int b = bh >> 4, hh = bh & 15;
#pragma unroll
  for (int qt = 0; qt < 2; ++qt) {
    float inv = co / lacc[qt][0];
    int nseq = rowbase + qt * 16 + m;
#pragma unroll
    for (int dt = 0; dt < 4; ++dt) {
      int c0 = hh * 64 + dt * 16 + q * 4;
      size_t midx = ((size_t)b * 2048 + nseq) * 1024 + c0;
      float4 xv = *(const float4*)(x + midx);
      ushort4 hv = make_ushort4(f2bf(cs * xv.x + oacc[qt][dt][0] * inv),
                                f2bf(cs * xv.y + oacc[qt][dt][1] * inv),
                                f2bf(cs * xv.z + oacc[qt][dt][2] * inv),
                                f2bf(cs * xv.w + oacc[qt][dt][3] * inv));
      *(ushort4*)(Hbf + midx) = hv;
    }
  }
}

// ============================================================================
extern "C" void kernel_launch(void* const* d_in, const int* in_sizes, int n_in,
                              void* d_out, int out_size, void* d_ws, size_t ws_size,
                              hipStream_t stream) {
  const float* x     = (const float*)d_in[0];
  const float* t     = (const float*)d_in[1];
  const float* Wqkv  = (const float*)d_in[2];
  const float* bqkv  = (const float*)d_in[3];
  const float* Wproj = (const float*)d_in[4];
  const float* bproj = (const float*)d_in[5];
  float* out = (float*)d_out;
  char* ws = (char*)d_ws;

  ushort_t* Xbf    = (ushort_t*)(ws + 256);
  ushort_t* WqkvT  = (ushort_t*)(ws + 256 + 16777216);
  ushort_t* WprojT = (ushort_t*)(ws + 256 + 16777216 + 6291456);
  ushort_t* Qb     = (ushort_t*)(ws + 256 + 16777216 + 6291456 + 2097152);
  ushort_t* Kb = Qb + 8388608;
  ushort_t* Vb = Kb + 8388608;
  ushort_t* Hb = Vb + 8388608;

  prep_kernel<<<12288, 256, 0, stream>>>(x, Xbf, Wqkv, WqkvT, Wproj, WprojT);
  gemm_qkv_kernel<<<6144, 64, 0, stream>>>(Xbf, WqkvT, bqkv, Qb, Kb, Vb);
  attn_kernel<<<1024, 256, 0, stream>>>(Qb, Kb, Vb, x, t, Hb);
  gemm_out_kernel<<<2048, 64, 0, stream>>>(Hb, WprojT, bproj, out);
}

// Round 13
// 244.285 us; speedup vs baseline: 1.2365x; 1.2365x over previous
//
#include <hip/hip_runtime.h>

// ============================================================================
// Fused rCM attention block: qkv-proj -> flash attention -> skip-fuse -> proj
// B=4, N=2048, C=1024, H=16, Dh=64.  All matmuls on bf16 MFMA (2% abs tol).
//
// R17: counted-vmcnt GEMM pipeline at the PROVEN 128x128 geometry.
//  R16 failed on traffic (64x64 tile doubled FETCH) + a broken swizzle, but
//  proved the counted-vmcnt idiom passes correctness. This round: 128^2
//  tile (R13 epilogues untouched), BK=64, dbuf, raw s_barrier + counted
//  waits -- NO vmcnt(0) drain in the loop (the structural stall R11/R14
//  isolated). Cross-wave hazard closed by ordering: each wave vmcnt(8)s
//  its OWN loads BEFORE s_barrier; reads AFTER -> barrier-exit implies all
//  waves' tile loads landed. Second barrier after lgkmcnt(0) frees the
//  buffer for stage(t+2). ds_read/stage swizzle formulas verbatim from
//  R14 (absmax-passed, SQ_LDS_BANK_CONFLICT=0 measured).
//  Ledger (8 loads/wave/K-tile): prologue T0,T1; group t: vmcnt(8) [T_t
//  landed, T_{t+1} flying; tail->0]; barrier; 16 ds_read; lgkm(0);
//  barrier; stage T_{t+2}->buf t&1; 32 MFMA.
// Carried: R12 4-dispatch pipeline, R13 grid stripe + epilogues, attn R13
//          (XCD swizzle, raw v_exp_f32), prep fusion.
// ============================================================================

typedef unsigned short ushort_t;
typedef __bf16 bf16x8 __attribute__((ext_vector_type(8)));
typedef float f32x4 __attribute__((ext_vector_type(4)));

#define GAS __attribute__((address_space(1)))
#define LAS __attribute__((address_space(3)))

static __device__ __forceinline__ ushort_t f2bf(float f) {
  union { float f; unsigned int u; } v; v.f = f;
  unsigned int r = v.u + 0x7fffu + ((v.u >> 16) & 1u);  // RNE
  return (ushort_t)(r >> 16);
}

static __device__ __forceinline__ void async16(const void* g, void* l) {
  __builtin_amdgcn_global_load_lds((const GAS unsigned int*)g,
                                   (LAS unsigned int*)l, 16, 0, 0);
}

// ----------------------------------------------------------- prep kernel ----
// blockIdx range dispatch:
//   [0, 8192)          : x fp32 -> bf16 (4 elems/thread)
//   [8192, 11264)      : Wqkv transpose+cvt (1024x3072 -> 3072x1024 bf16)
//   [11264, 12288)     : Wproj transpose+cvt (1024x1024 -> 1024x1024 bf16)
__global__ __launch_bounds__(256) void prep_kernel(
    const float* __restrict__ x, ushort_t* __restrict__ Xbf,
    const float* __restrict__ Wqkv, ushort_t* __restrict__ WqkvT,
    const float* __restrict__ Wproj, ushort_t* __restrict__ WprojT) {
  __shared__ float tile[32][33];
  const int bid = (int)blockIdx.x, tid = threadIdx.x;
  if (bid < 8192) {
    int i = (bid * 256 + tid) * 4;
    float4 v = *(const float4*)(x + i);
    ushort4 o = make_ushort4(f2bf(v.x), f2bf(v.y), f2bf(v.z), f2bf(v.w));
    *(ushort4*)(Xbf + i) = o;
    return;
  }
  const float* in;
  ushort_t* out;
  int R, C, bx, by;
  if (bid < 11264) {
    int q = bid - 8192;
    by = q / 96; bx = q - by * 96;
    in = Wqkv; out = WqkvT; R = 1024; C = 3072;
  } else {
    int p = bid - 11264;
    bx = p & 31; by = p >> 5;
    in = Wproj; out = WprojT; R = 1024; C = 1024;
  }
  int bc = bx * 32, br = by * 32;
  int tx = tid & 31, ty = tid >> 5;
#pragma unroll
  for (int i = 0; i < 32; i += 8)
    tile[ty + i][tx] = in[(size_t)(br + ty + i) * C + bc + tx];
  __syncthreads();
#pragma unroll
  for (int i = 0; i < 32; i += 8)
    out[(size_t)(bc + ty + i) * R + br + tx] = f2bf(tile[tx][ty + i]);
}

// ------------------------------ 128x128 GEMM core, BK=64, counted vmcnt ----
// LDS: As/Bs[2][128*64] bf16 (64KB total, 2 blocks/CU). Rows = 64 bf16 =
// 8 chunks of 16B; LDS position p of row r holds global chunk p^(r&7)
// (pre-swizzled source, linear wave-uniform dest -- R14-verified, 0
// conflicts). Read: chunk (ks*4+quad)^(lr&7) at row (w* + i*16 + lr)
// yields global chunk ks*4+quad (row&7 == lr&7).
// Sync per K-tile t: vmcnt(8) -> s_barrier -> 16 ds_read_b128 -> lgkm(0)
// -> s_barrier -> stage(t+2, buf t&1) -> 32 MFMA.  No vmcnt(0) in loop.
static __device__ __forceinline__ void gemm128_core(
    const ushort_t* __restrict__ A, const ushort_t* __restrict__ Bt, int K,
    int m0, int n0, ushort_t* As, ushort_t* Bs, f32x4 acc[4][4]) {
  const int tid = threadIdx.x;
  const int wave = tid >> 6, lane = tid & 63;
  const int wm = (wave >> 1) * 64, wn = (wave & 1) * 64;
  const int lr = lane & 15, quad = lane >> 4;
  const int lm = lr & 7;

  auto stage = [&](int kb, int buf) {
#pragma unroll
    for (int u = 0; u < 4; ++u) {
      int f = u * 256 + tid;
      int r = f >> 3, g = (f & 7) ^ (r & 7);   // pre-swizzled source chunk
      async16(A + (size_t)(m0 + r) * K + kb + g * 8,
              As + buf * 8192 + (u * 256 + wave * 64) * 8);
      async16(Bt + (size_t)(n0 + r) * K + kb + g * 8,
              Bs + buf * 8192 + (u * 256 + wave * 64) * 8);
    }
  };
  stage(0, 0);
  stage(64, 1);

  const int nt = K >> 6;   // 16 K-tiles
#pragma unroll 2
  for (int t = 0; t < nt; ++t) {
    const int cur = t & 1;
    // own tile-t loads landed (t+1 stays in flight); barrier => ALL waves'
    if (t + 1 < nt) asm volatile("s_waitcnt vmcnt(8)" ::: "memory");
    else            asm volatile("s_waitcnt vmcnt(0)" ::: "memory");
    __builtin_amdgcn_s_barrier();
    __builtin_amdgcn_sched_barrier(0);
    const ushort_t* As0 = As + cur * 8192;
    const ushort_t* Bs0 = Bs + cur * 8192;
    bf16x8 af[4][2], bfr[4][2];
#pragma unroll
    for (int i = 0; i < 4; ++i)
#pragma unroll
      for (int ks = 0; ks < 2; ++ks) {
        int pos = ((ks * 4 + quad) ^ lm) * 8;
        af[i][ks]  = *(const bf16x8*)(As0 + (wm + i * 16 + lr) * 64 + pos);
        bfr[i][ks] = *(const bf16x8*)(Bs0 + (wn + i * 16 + lr) * 64 + pos);
      }
    asm volatile("s_waitcnt lgkmcnt(0)" ::: "memory");
    __builtin_amdgcn_sched_barrier(0);
    __builtin_amdgcn_s_barrier();          // all waves' reads retired -> buf free
    __builtin_amdgcn_sched_barrier(0);
    if (t + 2 < nt) stage((t + 2) << 6, cur);
#pragma unroll
    for (int i = 0; i < 4; ++i)
#pragma unroll
      for (int j = 0; j < 4; ++j)
#pragma unroll
        for (int ks = 0; ks < 2; ++ks)
          acc[i][j] = __builtin_amdgcn_mfma_f32_16x16x32_bf16(af[i][ks], bfr[j][ks],
                                                              acc[i][j], 0, 0, 0);
  }
}

// XCD-stripe grid decode (R13, measured-neutral): bijective for 64m x Nn.
static __device__ __forceinline__ void grid_decode(int bid, int& m0, int& n0) {
  m0 = (((bid & 7) << 3) | ((bid >> 3) & 7)) << 7;
  n0 = (bid >> 6) << 7;
}

// ------------------------------------------------------------ QKV GEMM -----
// X[8192][1024] @ Wqkv -> Q (pre-scaled by 0.125*log2e), K bf16 [B,H,N,Dh];
// V bf16 [B,H,Dh,N'] with PV-frag key permutation. bias fused.
__global__ __launch_bounds__(256) void gemm_qkv_kernel(
    const ushort_t* __restrict__ Xbf, const ushort_t* __restrict__ Wt,
    const float* __restrict__ bqkv, ushort_t* __restrict__ Qb,
    ushort_t* __restrict__ Kb, ushort_t* __restrict__ Vb) {
  __shared__ __align__(16) ushort_t As[2 * 128 * 64];
  __shared__ __align__(16) ushort_t Bs[2 * 128 * 64];
  int m0, n0;
  grid_decode((int)blockIdx.x, m0, n0);
  f32x4 acc[4][4];
#pragma unroll
  for (int i = 0; i < 4; ++i)
#pragma unroll
    for (int j = 0; j < 4; ++j) acc[i][j] = f32x4{0.f, 0.f, 0.f, 0.f};
  gemm128_core(Xbf, Wt, 1024, m0, n0, As, Bs, acc);

  const int tid = threadIdx.x, wave = tid >> 6, lane = tid & 63;
  const int wm = (wave >> 1) * 64, wn = (wave & 1) * 64;
  const int col = lane & 15, quad = lane >> 4;
  const int b = m0 >> 11;
  const float C1 = 0.18033688011112042f;  // 0.125 * log2(e)
#pragma unroll
  for (int j = 0; j < 4; ++j) {
    int jc = n0 + wn + j * 16 + col;
    float bj = bqkv[jc];
    int which = jc >> 10, rem = jc & 1023;
    int hh = rem >> 6, d = rem & 63;
    if (which == 2) {
      size_t vb2 = ((size_t)(b * 16 + hh) * 64 + d) * 2048;
#pragma unroll
      for (int i = 0; i < 4; ++i) {
        int nbase = (m0 + wm + i * 16 + quad * 4) & 2047;
        // PV-frag permutation: n' = p*32 + qq*8 + sh*4 + rr
        int npos = (nbase & ~31) | (((nbase >> 2) & 3) << 3) | (((nbase >> 4) & 1) << 2);
        ushort4 pk = make_ushort4(f2bf(acc[i][j][0] + bj), f2bf(acc[i][j][1] + bj),
                                  f2bf(acc[i][j][2] + bj), f2bf(acc[i][j][3] + bj));
        *(ushort4*)(Vb + vb2 + npos) = pk;
      }
    } else {
      ushort_t* dst = which == 0 ? Qb : Kb;
      float sc = which == 0 ? C1 : 1.0f;
      size_t base = ((size_t)(b * 16 + hh) * 2048) * 64 + d;
#pragma unroll
      for (int i = 0; i < 4; ++i)
#pragma unroll
        for (int r = 0; r < 4; ++r) {
          int nseq = (m0 + wm + i * 16 + quad * 4 + r) & 2047;
          dst[base + (size_t)nseq * 64] = f2bf((acc[i][j][r] + bj) * sc);
        }
    }
  }
}

// ------------------------------------------------------------ Out GEMM -----
__global__ __launch_bounds__(256) void gemm_out_kernel(
    const ushort_t* __restrict__ Hbf, const ushort_t* __restrict__ Wt,
    const float* __restrict__ bproj, float* __restrict__ out) {
  __shared__ __align__(16) ushort_t As[2 * 128 * 64];
  __shared__ __align__(16) ushort_t Bs[2 * 128 * 64];
  int m0, n0;
  grid_decode((int)blockIdx.x, m0, n0);
  f32x4 acc[4][4];
#pragma unroll
  for (int i = 0; i < 4; ++i)
#pragma unroll
    for (int j = 0; j < 4; ++j) acc[i][j] = f32x4{0.f, 0.f, 0.f, 0.f};
  gemm128_core(Hbf, Wt, 1024, m0, n0, As, Bs, acc);

  const int tid = threadIdx.x, wave = tid >> 6, lane = tid & 63;
  const int wm = (wave >> 1) * 64, wn = (wave & 1) * 64;
  const int col = lane & 15, quad = lane >> 4;
#pragma unroll
  for (int j = 0; j < 4; ++j) {
    int jc = n0 + wn + j * 16 + col;
    float bj = bproj[jc];
#pragma unroll
    for (int i = 0; i < 4; ++i)
#pragma unroll
      for (int r = 0; r < 4; ++r) {
        int m = m0 + wm + i * 16 + quad * 4 + r;
        out[(size_t)m * 1024 + jc] = acc[i][j][r] + bj;
      }
  }
}

// ------------------------------------------------------ flash attention ----
// Block = 128 Q-rows (4 waves x 32 rows = 2 qtiles of 16); 64-key tiles,
// double-buffered, one barrier per tile. Per 32-key pair: 8 QK MFMAs (S^T),
// 32 exp + 16 perm, 8 PV + 2 l-MFMAs; V-frag = one b128 read.
// Chunked XCD swizzle: XCD x serves bh in [8x,8x+8) -> 4MB KV set per L2.
// Skip coefficients computed inline from t (coeff kernel folded in).
__global__ __launch_bounds__(256, 4) void attn_kernel(
    const ushort_t* __restrict__ Qb, const ushort_t* __restrict__ Kb,
    const ushort_t* __restrict__ Vb, const float* __restrict__ x,
    const float* __restrict__ t, ushort_t* __restrict__ Hbf) {
  // Ks[buf][key r][d]: 8-elem chunk at position p holds global chunk p^(r&7)
  // Vs[buf][d][key']: 8-key chunk at position p holds global chunk p^(d&7)
  __shared__ __align__(16) ushort_t Ks[2][64 * 64];
  __shared__ __align__(16) ushort_t Vs[2][64 * 64];

  const int tid = threadIdx.x, w = tid >> 6, lane = tid & 63;
  const int m = lane & 15, q = lane >> 4;
  // bijective chunked XCD swizzle (grid 1024 = 8 XCD x 128)
  const int bid = (int)blockIdx.x;
  const int wg = (bid & 7) * 128 + (bid >> 3);
  const int bh = wg >> 4, rowbase = ((wg & 15) << 7) + w * 32;

  const ushort_t* Qg = Qb + ((size_t)bh * 2048 + rowbase) * 64;
  const ushort_t* Kg = Kb + (size_t)bh * 2048 * 64;
  const ushort_t* Vg = Vb + (size_t)bh * 64 * 2048;  // [d][n']

  bf16x8 qf[2][2];
#pragma unroll
  for (int qt = 0; qt < 2; ++qt) {
    qf[qt][0] = *(const bf16x8*)(Qg + (qt * 16 + m) * 64 + q * 8);
    qf[qt][1] = *(const bf16x8*)(Qg + (qt * 16 + m) * 64 + 32 + q * 8);
  }

  auto stage = [&](int kt, int buf) {
#pragma unroll
    for (int i = 0; i < 2; ++i) {   // K: 64 keys x 64 d, swizzled
      int f = i * 256 + tid;
      int r = f >> 3, g = (f & 7) ^ (r & 7);
      async16(Kg + (size_t)(kt * 64 + r) * 64 + g * 8,
              Ks[buf] + (size_t)(i * 256 + w * 64) * 8);
    }
#pragma unroll
    for (int i = 0; i < 2; ++i) {   // V^T: 64 d x 64 keys, swizzled
      int f = i * 256 + tid;
      int d = f >> 3, g = (f & 7) ^ (d & 7);
      async16(Vg + (size_t)d * 2048 + kt * 64 + g * 8,
              Vs[buf] + (size_t)(i * 256 + w * 64) * 8);
    }
  };
  stage(0, 0);

  f32x4 oacc[2][4], lacc[2];
#pragma unroll
  for (int qt = 0; qt < 2; ++qt) {
    lacc[qt] = f32x4{0.f, 0.f, 0.f, 0.f};
#pragma unroll
    for (int dt = 0; dt < 4; ++dt) oacc[qt][dt] = f32x4{0.f, 0.f, 0.f, 0.f};
  }

  const float C2 = -23.083120654223414f;  // -16*log2(e)
  const f32x4 c2v = {C2, C2, C2, C2};
  const int mk = m & 7;
  union { bf16x8 v; unsigned int u[4]; } onesu;
#pragma unroll
  for (int h = 0; h < 4; ++h) onesu.u[h] = 0x3F803F80u;  // bf16 1.0 x2
  const bf16x8 ones = onesu.v;

#pragma unroll 2
  for (int kt = 0; kt < 32; ++kt) {
    const int cur = kt & 1;
    __syncthreads();                       // tile kt staged & prior reads done
    if (kt < 31) stage(kt + 1, cur ^ 1);   // prefetch in flight during compute
    const ushort_t* K0 = Ks[cur];
    const ushort_t* V0 = Vs[cur];

#pragma unroll
    for (int p = 0; p < 2; ++p) {          // 32-key pair of 16-key subtiles
      // ---- S^T: A = K-frag, B = Q-frag ----
      f32x4 st[2][2];
#pragma unroll
      for (int sh = 0; sh < 2; ++sh) {
        int s = p * 2 + sh;
        bf16x8 kf0 = *(const bf16x8*)(K0 + (s * 16 + m) * 64 + (q ^ mk) * 8);
        bf16x8 kf1 = *(const bf16x8*)(K0 + (s * 16 + m) * 64 + ((q + 4) ^ mk) * 8);
#pragma unroll
        for (int qt = 0; qt < 2; ++qt) {
          f32x4 a = __builtin_amdgcn_mfma_f32_16x16x32_bf16(kf0, qf[qt][0], c2v, 0, 0, 0);
          st[sh][qt] = __builtin_amdgcn_mfma_f32_16x16x32_bf16(kf1, qf[qt][1], a, 0, 0, 0);
        }
      }
      // ---- exp + truncating pack into PV B-frags (k = q*8 + sh*4 + rr) ----
      bf16x8 pf[2];
#pragma unroll
      for (int qt = 0; qt < 2; ++qt) {
        float pv[8];
#pragma unroll
        for (int sh = 0; sh < 2; ++sh)
#pragma unroll
          for (int rr = 0; rr < 4; ++rr)
            pv[sh * 4 + rr] = __builtin_amdgcn_exp2f(st[sh][qt][rr]);  // raw v_exp_f32
        union { bf16x8 v; unsigned int u[4]; } pk;
#pragma unroll
        for (int h = 0; h < 4; ++h)
          pk.u[h] = __builtin_amdgcn_perm(__float_as_uint(pv[2 * h + 1]),
                                          __float_as_uint(pv[2 * h]), 0x07060302);
        pf[qt] = pk.v;
      }
      // ---- O^T += V'-frag @ P^T; l += ones @ P^T (all on MFMA pipe) ----
#pragma unroll
      for (int dt = 0; dt < 4; ++dt) {
        bf16x8 vf = *(const bf16x8*)(V0 + (dt * 16 + m) * 64 + ((p * 4 + q) ^ mk) * 8);
#pragma unroll
        for (int qt = 0; qt < 2; ++qt)
          oacc[qt][dt] = __builtin_amdgcn_mfma_f32_16x16x32_bf16(vf, pf[qt], oacc[qt][dt], 0, 0, 0);
      }
#pragma unroll
      for (int qt = 0; qt < 2; ++qt)
        lacc[qt] = __builtin_amdgcn_mfma_f32_16x16x32_bf16(ones, pf[qt], lacc[qt], 0, 0, 0);
    }
  }

  // ---- epilogue: h = c_skip*x + c_out*(o/l); l = lacc[qt][0] (col = m) ----
  // skip coefficients inline (was coeff_kernel): mean over the 4 batch t's
  float cs = 0.f, co = 0.f;
#pragma unroll
  for (int i = 0; i < 4; ++i) {
    float ti = t[i];
    float d = 1.f + ti * ti;        // sigma_data = 1
    cs += 1.f / d;
    co += ti / sqrtf(d);
  }
  cs *= 0.25f; co *= 0.25f;

  const int b = bh >> 4, hh = bh & 15;
#pragma unroll
  for (int qt = 0; qt < 2; ++qt) {
    float inv = co / lacc[qt][0];
    int nseq = rowbase + qt * 16 + m;
#pragma unroll
    for (int dt = 0; dt < 4; ++dt) {
      int c0 = hh * 64 + dt * 16 + q * 4;
      size_t midx = ((size_t)b * 2048 + nseq) * 1024 + c0;
      float4 xv = *(const float4*)(x + midx);
      ushort4 hv = make_ushort4(f2bf(cs * xv.x + oacc[qt][dt][0] * inv),
                                f2bf(cs * xv.y + oacc[qt][dt][1] * inv),
                                f2bf(cs * xv.z + oacc[qt][dt][2] * inv),
                                f2bf(cs * xv.w + oacc[qt][dt][3] * inv));
      *(ushort4*)(Hbf + midx) = hv;
    }
  }
}

// ============================================================================
extern "C" void kernel_launch(void* const* d_in, const int* in_sizes, int n_in,
                              void* d_out, int out_size, void* d_ws, size_t ws_size,
                              hipStream_t stream) {
  const float* x     = (const float*)d_in[0];
  const float* t     = (const float*)d_in[1];
  const float* Wqkv  = (const float*)d_in[2];
  const float* bqkv  = (const float*)d_in[3];
  const float* Wproj = (const float*)d_in[4];
  const float* bproj = (const float*)d_in[5];
  float* out = (float*)d_out;
  char* ws = (char*)d_ws;

  ushort_t* Xbf    = (ushort_t*)(ws + 256);
  ushort_t* WqkvT  = (ushort_t*)(ws + 256 + 16777216);
  ushort_t* WprojT = (ushort_t*)(ws + 256 + 16777216 + 6291456);
  ushort_t* Qb     = (ushort_t*)(ws + 256 + 16777216 + 6291456 + 2097152);
  ushort_t* Kb = Qb + 8388608;
  ushort_t* Vb = Kb + 8388608;
  ushort_t* Hb = Vb + 8388608;

  prep_kernel<<<12288, 256, 0, stream>>>(x, Xbf, Wqkv, WqkvT, Wproj, WprojT);
  gemm_qkv_kernel<<<1536, 256, 0, stream>>>(Xbf, WqkvT, bqkv, Qb, Kb, Vb);
  attn_kernel<<<1024, 256, 0, stream>>>(Qb, Kb, Vb, x, t, Hb);
  gemm_out_kernel<<<512, 256, 0, stream>>>(Hb, WprojT, bproj, out);
}